// Round 11
// baseline (561.335 us; speedup 1.0000x reference)
//
#include <hip/hip_runtime.h>
#include <math.h>

// Clusterator soft k-means: N=200000, D=256, K=64, 11 iterations.
// v13: v11 (491.9us best) + ONLY the convert-pass read-order fix
//     (q = i2^sub on the x32 fp32 LDS read -- was an 8-way bank conflict:
//     g&7==i2 constant per instruction -> 2 bank-groups/quarter-wave; now all
//     8 groups hit). v12's stage-overlap is REVERTED (it caused L2
//     partial-sector eviction: WRITE_SIZE 118->200MB, +35us). Stage stays
//     serial at tile top; Xh write order stays v11's (measured clean).
//     cluster_main8 / reduce_mu: v11 VERBATIM.
// v1 fallback (round-1 fp32 kernel) if ws_size too small.

#define N_ROWS 200000
#define DIM 256
#define KC 64
#define NUM_ITER 11
#define TR 64
#define NTILES (N_ROWS / TR)  // 3125
#define EPSV 1e-8f
#define NB 256

typedef _Float16 half8 __attribute__((ext_vector_type(8)));
typedef _Float16 half4 __attribute__((ext_vector_type(4)));
typedef float f32x4 __attribute__((ext_vector_type(4)));

typedef __attribute__((address_space(3))) void as3_void;
typedef __attribute__((address_space(1))) void as1_void;

__device__ __forceinline__ void glds16(const void* g, void* l) {
  __builtin_amdgcn_global_load_lds((const as1_void*)g, (as3_void*)l, 16, 0, 0);
}

__device__ __forceinline__ float wave_reduce_sum(float v) {
#pragma unroll
  for (int off = 32; off > 0; off >>= 1) v += __shfl_xor(v, off, 64);
  return v;
}

// LDS-only barrier: orders ds_write -> barrier -> ds_read across waves without
// draining vmcnt (global_load_lds prefetches stay in flight across it).
__device__ __forceinline__ void barrier_lgkm_only() {
  __builtin_amdgcn_sched_barrier(0);
  asm volatile("s_waitcnt lgkmcnt(0)" ::: "memory");
  __builtin_amdgcn_s_barrier();
  __builtin_amdgcn_sched_barrier(0);
}

// ---------------- staging helper (8-wave) ----------------
// 512B-row arrays (X tile rows): 32 x 1KB chunks, swizzled source, 4/wave.
// LDS layout: elem(row,dim) at [row*DIM + (dim ^ ((row&7)<<3))]
__device__ __forceinline__ void stage_row512_8(const _Float16* g, _Float16* l,
                                               int wid, int lane) {
#pragma unroll
  for (int ii = 0; ii < 4; ++ii) {
    int i = wid * 4 + ii;
    int row = i * 2 + (lane >> 5);
    int slot = (lane & 31) ^ (row & 7);
    glds16((const char*)g + row * 512 + slot * 16, (char*)l + i * 1024);
  }
}

// ---------------- iteration-0 kernel: fp32 in, prep fused ----------------
__global__ __launch_bounds__(512, 1) void cluster_first(
    const float* __restrict__ embeds, const float* __restrict__ init,
    const float* __restrict__ beta, _Float16* __restrict__ Xh,
    float* __restrict__ inv_norm, float* __restrict__ part_cm,
    float* __restrict__ part_crt) {
  __shared__ alignas(16) _Float16 x_lds[2][TR * DIM];    // 64KB: f32 stage, then XT target
  __shared__ alignas(16) _Float16 xt_lds[DIM * TR];      // 32KB: f16 X tile [row][dim] swz
  __shared__ alignas(16) _Float16 mu_lds[KC * DIM];      // 32KB [cl][dim] swz
  __shared__ alignas(16) _Float16 r_lds[KC * TR];        // 8KB  [cl][row] swz
  __shared__ alignas(16) f32x4 dist_lds[16 * 64];        // 16KB K-split partials
  __shared__ float cr_lds[4 * KC];                       // 1KB
  __shared__ float inv_lds[TR];                          // per-tile row inv

  float* x32 = (float*)&x_lds[0][0];        // 16384 f32 = 64 rows x 1KB
  _Float16* xtile = xt_lds;                 // f16 X tile (v9 x layout)
  _Float16* xtr = &x_lds[0][0];             // XT target (v9 xt layout)

  const int tid = threadIdx.x, wid = tid >> 6, lane = tid & 63;
  const int l15 = lane & 15, h = lane >> 4;
  const int kh = wid >> 2, rg = wid & 3;
  const float b = beta[0];
  const int myrow = 16 * rg + l15;
  const int rb0 = blockIdx.x;

  // ===== mu prologue from init (fp32): ssq -> rsqrt -> normalized f16 =====
  {
    const int cl = tid >> 3, sub = tid & 7;
    float ss = 0.f;
#pragma unroll
    for (int j = 0; j < 8; ++j) {
      float4 v = *(const float4*)(init + (size_t)cl * DIM + sub * 32 + 4 * j);
      ss = fmaf(v.x, v.x, ss); ss = fmaf(v.y, v.y, ss);
      ss = fmaf(v.z, v.z, ss); ss = fmaf(v.w, v.w, ss);
    }
    ss += __shfl_xor(ss, 1); ss += __shfl_xor(ss, 2); ss += __shfl_xor(ss, 4);
    if (sub == 0) cr_lds[cl] = ss;
  }
  __syncthreads();
  if (tid < KC) cr_lds[tid] = 1.0f / fmaxf(sqrtf(cr_lds[tid]), EPSV);
  __syncthreads();
  {
    const float4* init4 = (const float4*)init;
#pragma unroll
    for (int i = 0; i < 8; ++i) {
      const int idx = tid + 512 * i;
      const int cl = idx >> 6;
      const int dim0 = (idx & 63) * 4;
      float4 v = init4[idx];
      const float iv = cr_lds[cl];
      const int sw = dim0 ^ ((cl & 7) << 3);
      half4 hh;
      hh[0] = (_Float16)(v.x * iv); hh[1] = (_Float16)(v.y * iv);
      hh[2] = (_Float16)(v.z * iv); hh[3] = (_Float16)(v.w * iv);
      *(half4*)&mu_lds[cl * DIM + sw] = hh;
    }
  }
  __syncthreads();
  half8 amreg[4][4];  // K-split mu fragments (v9)
#pragma unroll
  for (int t = 0; t < 4; ++t) {
    const int kb = 128 * kh + 32 * t + 8 * h;
#pragma unroll
    for (int m = 0; m < 4; ++m) {
      const int cl = 16 * m + l15;
      amreg[t][m] = *(const half8*)&mu_lds[cl * DIM + (kb ^ ((cl & 7) << 3))];
    }
  }

  f32x4 acc2[4][2] = {};
  float cr_acc[16] = {};
  for (int rb = rb0; rb < NTILES; rb += NB) {
    // ---- stage fp32 tile: 64 rows x 1KB, one row per chunk, 8/wave ----
#pragma unroll
    for (int ii = 0; ii < 8; ++ii) {
      const int row = wid * 8 + ii;
      const int slot = lane ^ (row & 7);
      glds16((const char*)embeds + (size_t)(rb * TR + row) * 1024 + slot * 16,
             (char*)x32 + row * 1024);
    }
    __syncthreads();  // f32 staged (vmcnt drained by barrier semantics)

    // ---- fused pass: row ssq + f16 convert (LDS + global Xh) + inv ----
    // v13: read visit-order q = i2^sub makes g&7 = i2^sub vary per lane ->
    // all 8 bank-16-groups hit per instruction (was 8-way conflict).
    {
      const int row = tid >> 3, sub = tid & 7;
      float ss = 0.f;
      half8 hh[4];
#pragma unroll
      for (int i2 = 0; i2 < 8; ++i2) {
        const int q = i2 ^ sub;          // this thread's float4 index 0..7
        const int g = sub * 8 + q;       // row-global float4 index 0..63
        float4 v = *(const float4*)((const char*)x32 + row * 1024 +
                                    ((g ^ (row & 7)) * 16));
        ss = fmaf(v.x, v.x, ss); ss = fmaf(v.y, v.y, ss);
        ss = fmaf(v.z, v.z, ss); ss = fmaf(v.w, v.w, ss);
        _Float16* hp = (_Float16*)&hh[q >> 1] + (q & 1) * 4;
        hp[0] = (_Float16)v.x; hp[1] = (_Float16)v.y;
        hp[2] = (_Float16)v.z; hp[3] = (_Float16)v.w;
      }
#pragma unroll
      for (int j = 0; j < 4; ++j) {      // v11 write order (measured clean)
        const int slot = (sub * 4 + j) ^ (row & 7);
        *(half8*)((char*)xtile + row * 512 + slot * 16) = hh[j];
        *(float4*)((char*)Xh + (size_t)(rb * TR + row) * 512 + sub * 64 + j * 16) =
            *(float4*)&hh[j];
      }
      ss += __shfl_xor(ss, 1); ss += __shfl_xor(ss, 2); ss += __shfl_xor(ss, 4);
      if (sub == 0) {
        const float iv = 1.0f / fmaxf(sqrtf(ss), EPSV);
        inv_lds[row] = iv;
        inv_norm[rb * TR + row] = iv;
      }
    }
    barrier_lgkm_only();  // xtile + inv_lds visible (Xh stores stay in flight)

    // ---- GEMM1 (K-split, v9 body; xb = xtile) ----
    f32x4 acc1[4] = {};
#pragma unroll
    for (int t = 0; t < 4; ++t) {
      const int kb = 128 * kh + 32 * t + 8 * h;
      half8 bx = *(const half8*)&xtile[myrow * DIM + (kb ^ ((myrow & 7) << 3))];
#pragma unroll
      for (int m = 0; m < 4; ++m)
        acc1[m] = __builtin_amdgcn_mfma_f32_16x16x32_f16(amreg[t][m], bx, acc1[m], 0, 0, 0);
    }
    if (kh) {
#pragma unroll
      for (int m = 0; m < 4; ++m) dist_lds[(rg * 4 + m) * 64 + lane] = acc1[m];
    }
    barrier_lgkm_only();  // bar1

    if (!kh) {
      // ---- combine + softmax (waves 0-3); inv from LDS ----
#pragma unroll
      for (int m = 0; m < 4; ++m) acc1[m] += dist_lds[(rg * 4 + m) * 64 + lane];
      const float sc = b * inv_lds[myrow];
#pragma unroll
      for (int m = 0; m < 4; ++m)
#pragma unroll
        for (int j = 0; j < 4; ++j) acc1[m][j] *= sc;
      float mx = -1e30f;
#pragma unroll
      for (int m = 0; m < 4; ++m)
#pragma unroll
        for (int j = 0; j < 4; ++j) mx = fmaxf(mx, acc1[m][j]);
      mx = fmaxf(mx, __shfl_xor(mx, 16));
      mx = fmaxf(mx, __shfl_xor(mx, 32));
      float esum = 0.f;
#pragma unroll
      for (int m = 0; m < 4; ++m)
#pragma unroll
        for (int j = 0; j < 4; ++j) {
          float e = __expf(acc1[m][j] - mx);
          acc1[m][j] = e;
          esum += e;
        }
      esum += __shfl_xor(esum, 16);
      esum += __shfl_xor(esum, 32);
      const float rcp = 1.0f / esum;
#pragma unroll
      for (int m = 0; m < 4; ++m)
#pragma unroll
        for (int j = 0; j < 4; ++j) {
          const float rv = acc1[m][j] * rcp;
          const int cl = 16 * m + 4 * h + j;
          cr_acc[m * 4 + j] += rv;
          r_lds[cl * TR + (myrow ^ ((cl & 7) << 3))] = (_Float16)rv;
        }
    } else {
      // ---- in-LDS transpose xtile -> xtr (waves 4-7, v9 body) ----
      const int t8 = tid & 255;
      const int db = t8 >> 3, rb8 = t8 & 7;
      union U { uint4 v; unsigned u[4]; };
      U tin[8];
#pragma unroll
      for (int k2 = 0; k2 < 8; ++k2)
        tin[k2].v = *(const uint4*)&xtile[(8 * rb8 + k2) * DIM + ((8 * db) ^ (k2 << 3))];
#pragma unroll
      for (int j = 0; j < 8; ++j) {
        const unsigned sel = (j & 1) ? 0x07060302u : 0x05040100u;
        U o;
#pragma unroll
        for (int m2 = 0; m2 < 4; ++m2)
          o.u[m2] = __builtin_amdgcn_perm(tin[2 * m2 + 1].u[j >> 1],
                                          tin[2 * m2].u[j >> 1], sel);
        *(uint4*)&xtr[(8 * db + j) * TR + 8 * (rb8 ^ j)] = o.v;
      }
    }
    barrier_lgkm_only();  // bar2: r_lds + xtr visible

    // ---- GEMM2 (N-split, v9 body; bx2 from xtr) ----
#pragma unroll
    for (int t = 0; t < 2; ++t) {
      const int kb = 32 * t + 8 * h;
      half8 ar[4], bx2[2];
#pragma unroll
      for (int m = 0; m < 4; ++m) {
        const int cl = 16 * m + l15;
        ar[m] = *(const half8*)&r_lds[cl * TR + (kb ^ ((cl & 7) << 3))];
      }
#pragma unroll
      for (int n = 0; n < 2; ++n) {
        const int dm = 32 * wid + 16 * n + l15;
        bx2[n] = *(const half8*)&xtr[dm * TR + (kb ^ ((dm & 7) << 3))];
      }
#pragma unroll
      for (int m = 0; m < 4; ++m)
#pragma unroll
        for (int n = 0; n < 2; ++n)
          acc2[m][n] = __builtin_amdgcn_mfma_f32_16x16x32_f16(ar[m], bx2[n], acc2[m][n], 0, 0, 0);
    }
    __syncthreads();  // tile end: xtr/x32 free; Xh stores drained
  }

  // ===== epilogue (v9) =====
  float* pc = part_cm + (size_t)blockIdx.x * (KC * DIM);
#pragma unroll
  for (int m = 0; m < 4; ++m)
#pragma unroll
    for (int n = 0; n < 2; ++n)
#pragma unroll
      for (int j = 0; j < 4; ++j)
        pc[(16 * m + 4 * h + j) * DIM + 32 * wid + 16 * n + l15] = acc2[m][n][j];
  if (wid < 4) {
#pragma unroll
    for (int m = 0; m < 4; ++m)
#pragma unroll
      for (int j = 0; j < 4; ++j) {
        float v = cr_acc[m * 4 + j];
        v += __shfl_xor(v, 1); v += __shfl_xor(v, 2);
        v += __shfl_xor(v, 4); v += __shfl_xor(v, 8);
        if (l15 == 0) cr_lds[wid * KC + 16 * m + 4 * h + j] = v;
      }
  }
  __syncthreads();
  if (wid == 0)
    part_crt[(size_t)lane * NB + blockIdx.x] =
        cr_lds[lane] + cr_lds[KC + lane] + cr_lds[2 * KC + lane] + cr_lds[3 * KC + lane];
}

// ---------------- main kernel (iterations 1..10): v9 VERBATIM ----------------
template <int LAST>
__global__ __launch_bounds__(512, 2) void cluster_main8(
    const _Float16* __restrict__ Xh, const float* __restrict__ inv_norm,
    const float* __restrict__ beta, const float* __restrict__ mu_raw,
    const float* __restrict__ mu_ssq, float* __restrict__ part_cm,
    float* __restrict__ part_crt, float* __restrict__ r_out) {
  __shared__ alignas(16) _Float16 mu_lds[KC * DIM];      // 32KB [cl][dim] swz
  __shared__ alignas(16) _Float16 x_lds[2][TR * DIM];    // 64KB [row][dim] swz
  __shared__ alignas(16) _Float16 xt_lds[DIM * TR];      // 32KB [dim][row] swz
  __shared__ alignas(16) _Float16 r_lds[KC * TR];        // 8KB  [cl][row] swz
  __shared__ alignas(16) f32x4 dist_lds[16 * 64];        // 16KB K-split partials
  __shared__ float cr_lds[4 * KC];                       // 1KB  mu inv / cr

  const int tid = threadIdx.x, wid = tid >> 6, lane = tid & 63;
  const int l15 = lane & 15, h = lane >> 4;
  const int kh = wid >> 2, rg = wid & 3;  // K-half, row-group
  const float b = beta[0];
  const int myrow = 16 * rg + l15;  // tile-local row this lane owns
  const int rb0 = blockIdx.x;

  // first X tile in flight
  stage_row512_8(Xh + (size_t)rb0 * TR * DIM, x_lds[0], wid, lane);

  // ===== mu prologue: normalize raw fp32 mu while staging into LDS =====
  if (tid < KC) {
    const float4 s4 = *(const float4*)&mu_ssq[4 * tid];
    cr_lds[tid] = 1.0f / fmaxf(sqrtf(s4.x + s4.y + s4.z + s4.w), EPSV);
  }
  __syncthreads();
  {
    const float4* mu_raw4 = (const float4*)mu_raw;
#pragma unroll
    for (int i = 0; i < 8; ++i) {
      const int idx = tid + 512 * i;          // 4096 float4 total
      const int cl = idx >> 6;                // 64 float4 per cluster row
      const int dim0 = (idx & 63) * 4;
      float4 v = mu_raw4[idx];
      const float iv = cr_lds[cl];
      const int sw = dim0 ^ ((cl & 7) << 3);
      half4 hh;
      hh[0] = (_Float16)(v.x * iv); hh[1] = (_Float16)(v.y * iv);
      hh[2] = (_Float16)(v.z * iv); hh[3] = (_Float16)(v.w * iv);
      *(half4*)&mu_lds[cl * DIM + sw] = hh;
    }
  }
  __syncthreads();  // mu_lds ready; x_lds[0] staging drained (vmcnt0)

  // hoist this wave's 16 loop-invariant mu fragments to registers.
  half8 amreg[4][4];
#pragma unroll
  for (int t = 0; t < 4; ++t) {
    const int kb = 128 * kh + 32 * t + 8 * h;
#pragma unroll
    for (int m = 0; m < 4; ++m) {
      const int cl = 16 * m + l15;
      amreg[t][m] = *(const half8*)&mu_lds[cl * DIM + (kb ^ ((cl & 7) << 3))];
    }
  }

  f32x4 acc2[4][2] = {};
  float cr_acc[16] = {};
  int p = 0;
  for (int rb = rb0; rb < NTILES; rb += NB, p ^= 1) {
    const int row0 = rb * TR;
    const int rbn = rb + NB;
    if (rbn < NTILES)  // prefetch next X tile into other buffer
      stage_row512_8(Xh + (size_t)rbn * TR * DIM, x_lds[p ^ 1], wid, lane);

    // ---- GEMM1 (K-split): mu from regs -> 4 LDS reads per wave ----
    f32x4 acc1[4] = {};
    const _Float16* xb = x_lds[p];
#pragma unroll
    for (int t = 0; t < 4; ++t) {
      const int kb = 128 * kh + 32 * t + 8 * h;
      half8 bx = *(const half8*)&xb[myrow * DIM + (kb ^ ((myrow & 7) << 3))];
#pragma unroll
      for (int m = 0; m < 4; ++m)
        acc1[m] = __builtin_amdgcn_mfma_f32_16x16x32_f16(amreg[t][m], bx, acc1[m], 0, 0, 0);
    }
    if (kh) {  // publish K-half partials
#pragma unroll
      for (int m = 0; m < 4; ++m) dist_lds[(rg * 4 + m) * 64 + lane] = acc1[m];
    }
    barrier_lgkm_only();  // bar1: dist partials visible; X prefetch in flight

    if (!kh) {
      // ---- combine + softmax over 64 clusters (waves 0-3) ----
#pragma unroll
      for (int m = 0; m < 4; ++m) acc1[m] += dist_lds[(rg * 4 + m) * 64 + lane];
      const int xr = row0 + myrow;
      const float sc = b * inv_norm[xr];
#pragma unroll
      for (int m = 0; m < 4; ++m)
#pragma unroll
        for (int j = 0; j < 4; ++j) acc1[m][j] *= sc;
      float mx = -1e30f;
#pragma unroll
      for (int m = 0; m < 4; ++m)
#pragma unroll
        for (int j = 0; j < 4; ++j) mx = fmaxf(mx, acc1[m][j]);
      mx = fmaxf(mx, __shfl_xor(mx, 16));
      mx = fmaxf(mx, __shfl_xor(mx, 32));
      float esum = 0.f;
#pragma unroll
      for (int m = 0; m < 4; ++m)
#pragma unroll
        for (int j = 0; j < 4; ++j) {
          float e = __expf(acc1[m][j] - mx);
          acc1[m][j] = e;
          esum += e;
        }
      esum += __shfl_xor(esum, 16);
      esum += __shfl_xor(esum, 32);
      const float rcp = 1.0f / esum;
#pragma unroll
      for (int m = 0; m < 4; ++m) {
#pragma unroll
        for (int j = 0; j < 4; ++j) {
          const float rv = acc1[m][j] * rcp;
          acc1[m][j] = rv;
          const int cl = 16 * m + 4 * h + j;
          cr_acc[m * 4 + j] += rv;
          r_lds[cl * TR + (myrow ^ ((cl & 7) << 3))] = (_Float16)rv;
        }
        if (LAST)  // coalesced 16B store
          *(float4*)&r_out[(size_t)xr * KC + 16 * m + 4 * h] = *(float4*)&acc1[m];
      }
    } else {
      // ---- in-LDS transpose x[p] -> xt_lds (waves 4-7, 8x8 via v_perm) ----
      const int t8 = tid & 255;
      const int db = t8 >> 3, rb8 = t8 & 7;
      union U { uint4 v; unsigned u[4]; };
      U tin[8];
#pragma unroll
      for (int k2 = 0; k2 < 8; ++k2)  // row = 8*rb8+k2 -> row&7 == k2
        tin[k2].v = *(const uint4*)&xb[(8 * rb8 + k2) * DIM + ((8 * db) ^ (k2 << 3))];
#pragma unroll
      for (int j = 0; j < 8; ++j) {
        const unsigned sel = (j & 1) ? 0x07060302u : 0x05040100u;
        U o;
#pragma unroll
        for (int m2 = 0; m2 < 4; ++m2)
          o.u[m2] = __builtin_amdgcn_perm(tin[2 * m2 + 1].u[j >> 1],
                                          tin[2 * m2].u[j >> 1], sel);
        *(uint4*)&xt_lds[(8 * db + j) * TR + 8 * (rb8 ^ j)] = o.v;
      }
    }

    barrier_lgkm_only();  // bar2: r_lds + xt_lds visible

    // ---- GEMM2 (N-split): wave wid owns dims 32*wid..+31 ----
#pragma unroll
    for (int t = 0; t < 2; ++t) {
      const int kb = 32 * t + 8 * h;
      half8 ar[4], bx2[2];
#pragma unroll
      for (int m = 0; m < 4; ++m) {
        const int cl = 16 * m + l15;
        ar[m] = *(const half8*)&r_lds[cl * TR + (kb ^ ((cl & 7) << 3))];
      }
#pragma unroll
      for (int n = 0; n < 2; ++n) {
        const int dm = 32 * wid + 16 * n + l15;
        bx2[n] = *(const half8*)&xt_lds[dm * TR + (kb ^ ((dm & 7) << 3))];
      }
#pragma unroll
      for (int m = 0; m < 4; ++m)
#pragma unroll
        for (int n = 0; n < 2; ++n)
          acc2[m][n] = __builtin_amdgcn_mfma_f32_16x16x32_f16(ar[m], bx2[n], acc2[m][n], 0, 0, 0);
    }
    // sync2: full drain -- next tile needs x[p^1] staged for all waves.
    __syncthreads();
  }

  // ===== epilogue: per-block partials =====
  float* pc = part_cm + (size_t)blockIdx.x * (KC * DIM);
#pragma unroll
  for (int m = 0; m < 4; ++m)
#pragma unroll
    for (int n = 0; n < 2; ++n)
#pragma unroll
      for (int j = 0; j < 4; ++j)
        pc[(16 * m + 4 * h + j) * DIM + 32 * wid + 16 * n + l15] = acc2[m][n][j];
  if (wid < 4) {
#pragma unroll
    for (int m = 0; m < 4; ++m)
#pragma unroll
      for (int j = 0; j < 4; ++j) {
        float v = cr_acc[m * 4 + j];
        v += __shfl_xor(v, 1); v += __shfl_xor(v, 2);
        v += __shfl_xor(v, 4); v += __shfl_xor(v, 8);
        if (l15 == 0) cr_lds[wid * KC + 16 * m + 4 * h + j] = v;
      }
  }
  __syncthreads();
  if (wid == 0)
    part_crt[(size_t)lane * NB + blockIdx.x] =  // transposed: [cl][block]
        cr_lds[lane] + cr_lds[KC + lane] + cr_lds[2 * KC + lane] + cr_lds[3 * KC + lane];
}

// ---------------- reduce: grid (KC,4), one (cluster, dim-quarter)/block ----
template <int FINAL>
__global__ void reduce_mu(const float* __restrict__ part_cm,
                          const float* __restrict__ part_crt,
                          float* __restrict__ mu_raw, float* __restrict__ mu_ssq,
                          float* __restrict__ mu_out) {
  const int cl = blockIdx.x, q = blockIdx.y;
  const int tid = threadIdx.x, wid = tid >> 6, lane = tid & 63;
  __shared__ float red2[4 * 64];
  __shared__ float cr4[4];
  float c = part_crt[(size_t)cl * NB + tid];  // coalesced 1KB
  c = wave_reduce_sum(c);
  if (lane == 0) cr4[wid] = c;
  float s = 0.f;
  const float* basep =
      part_cm + (size_t)(64 * wid) * (KC * DIM) + cl * DIM + 64 * q + lane;
#pragma unroll 8
  for (int i = 0; i < 64; ++i) s += basep[(size_t)i * (KC * DIM)];
  red2[wid * 64 + lane] = s;
  __syncthreads();
  if (wid == 0) {
    const float crv = cr4[0] + cr4[1] + cr4[2] + cr4[3];
    const float st = red2[lane] + red2[64 + lane] + red2[128 + lane] + red2[192 + lane];
    const float mu = st / crv;
    const int dim = 64 * q + lane;
    if (FINAL) {
      mu_out[cl * DIM + dim] = mu;
    } else {
      mu_raw[cl * DIM + dim] = mu;
      float ss = wave_reduce_sum(mu * mu);
      if (lane == 0) mu_ssq[cl * 4 + q] = ss;
    }
  }
}

// ================= v1 fallback (round-1 fp32 path) =================
__global__ void rownorm_v1(const float* __restrict__ embeds, float* __restrict__ inv_norm) {
  int gw = (blockIdx.x * blockDim.x + threadIdx.x) >> 6;
  int lane = threadIdx.x & 63;
  int nw = (gridDim.x * blockDim.x) >> 6;
  for (int row = gw; row < N_ROWS; row += nw) {
    const float* rp = embeds + (size_t)row * DIM;
    float s = 0.f;
#pragma unroll
    for (int j = 0; j < 4; ++j) { float v = rp[lane + 64 * j]; s = fmaf(v, v, s); }
    s = wave_reduce_sum(s);
    if (lane == 0) inv_norm[row] = 1.0f / fmaxf(sqrtf(s), EPSV);
  }
}
__global__ void prep0_v1(const float* __restrict__ init, float* __restrict__ muT) {
  int k = blockIdx.x, lane = threadIdx.x;
  const float* rp = init + k * DIM;
  float v[4]; float s = 0.f;
#pragma unroll
  for (int j = 0; j < 4; ++j) { v[j] = rp[lane + 64 * j]; s = fmaf(v[j], v[j], s); }
  s = wave_reduce_sum(s);
  float inv = 1.0f / fmaxf(sqrtf(s), EPSV);
#pragma unroll
  for (int j = 0; j < 4; ++j) muT[(lane + 64 * j) * KC + k] = v[j] * inv;
}
__device__ __forceinline__ float wave_reduce_max_v1(float v) {
#pragma unroll
  for (int off = 32; off > 0; off >>= 1) v = fmaxf(v, __shfl_xor(v, off, 64));
  return v;
}
template <int LAST>
__global__ __launch_bounds__(256, 1) void main_v1(
    const float* __restrict__ embeds, const float* __restrict__ inv_norm,
    const float* __restrict__ muT, const float* __restrict__ beta,
    float* __restrict__ part_cm, float* __restrict__ part_cr,
    float* __restrict__ r_out, int nb) {
  __shared__ float mu_l[DIM * KC];
  __shared__ float x_l[TR * DIM];
  __shared__ float r_l[TR * KC];
  __shared__ float cr_l[4 * KC];
  const int tid = threadIdx.x, wid = tid >> 6, lane = tid & 63;
  const float b = beta[0];
  {
    const float4* m4 = (const float4*)muT; float4* ml4 = (float4*)mu_l;
#pragma unroll
    for (int i = 0; i < 16; ++i) ml4[tid + i * 256] = m4[tid + i * 256];
  }
  float acc[64];
#pragma unroll
  for (int i = 0; i < 64; ++i) acc[i] = 0.f;
  float cr = 0.f;
  for (int rb = blockIdx.x; rb < NTILES; rb += nb) {
    const int row0 = rb * TR;
    __syncthreads();
    {
      const float4* x4 = (const float4*)(embeds + (size_t)row0 * DIM);
      float4* xl4 = (float4*)x_l;
#pragma unroll
      for (int i = 0; i < 16; ++i) xl4[tid + i * 256] = x4[tid + i * 256];
    }
    __syncthreads();
    float dist[16];
#pragma unroll
    for (int r = 0; r < 16; ++r) dist[r] = 0.f;
    const int rbase = wid * 16;
    for (int d = 0; d < DIM; d += 4) {
      float mv0 = mu_l[(d + 0) * KC + lane], mv1 = mu_l[(d + 1) * KC + lane];
      float mv2 = mu_l[(d + 2) * KC + lane], mv3 = mu_l[(d + 3) * KC + lane];
#pragma unroll
      for (int r = 0; r < 16; ++r) {
        float4 xv = *(const float4*)&x_l[(rbase + r) * DIM + d];
        dist[r] = fmaf(xv.x, mv0, dist[r]); dist[r] = fmaf(xv.y, mv1, dist[r]);
        dist[r] = fmaf(xv.z, mv2, dist[r]); dist[r] = fmaf(xv.w, mv3, dist[r]);
      }
    }
#pragma unroll
    for (int r = 0; r < 16; ++r) {
      const int row = rbase + r;
      float s = b * (dist[r] * inv_norm[row0 + row]);
      float m = wave_reduce_max_v1(s);
      float e = __expf(s - m);
      float sum = wave_reduce_sum(e);
      float rv = e * (1.0f / sum);
      cr += rv;
      r_l[row * KC + lane] = rv;
      if (LAST) r_out[(size_t)(row0 + row) * KC + lane] = rv;
    }
    __syncthreads();
    const int dbase = wid * 64;
    for (int row = 0; row < TR; ++row) {
      float rv = r_l[row * KC + lane];
#pragma unroll
      for (int dd = 0; dd < 64; dd += 4) {
        float4 xv = *(const float4*)&x_l[row * DIM + dbase + dd];
        acc[dd + 0] = fmaf(rv, xv.x, acc[dd + 0]); acc[dd + 1] = fmaf(rv, xv.y, acc[dd + 1]);
        acc[dd + 2] = fmaf(rv, xv.z, acc[dd + 2]); acc[dd + 3] = fmaf(rv, xv.w, acc[dd + 3]);
      }
    }
  }
  {
    float* pp = part_cm + ((size_t)blockIdx.x * KC + lane) * DIM + wid * 64;
#pragma unroll
    for (int dd = 0; dd < 64; dd += 4)
      *(float4*)&pp[dd] = make_float4(acc[dd], acc[dd + 1], acc[dd + 2], acc[dd + 3]);
    cr_l[wid * KC + lane] = cr;
  }
  __syncthreads();
  if (wid == 0) {
    float c = cr_l[lane] + cr_l[64 + lane] + cr_l[128 + lane] + cr_l[192 + lane];
    part_cr[(size_t)blockIdx.x * KC + lane] = c;
  }
}
template <int FINAL>
__global__ void reduce_v1(const float* __restrict__ part_cm, const float* __restrict__ part_cr,
                          float* __restrict__ muT, float* __restrict__ mu_out, int nb) {
  const int k = blockIdx.x, t = threadIdx.x;
  __shared__ float red[256];
  float s = 0.f;
  for (int bl = 0; bl < nb; ++bl) s += part_cm[((size_t)bl * KC + k) * DIM + t];
  float c = 0.f;
  for (int bl = t; bl < nb; bl += 256) c += part_cr[(size_t)bl * KC + k];
  red[t] = c; __syncthreads();
#pragma unroll
  for (int off = 128; off > 0; off >>= 1) { if (t < off) red[t] += red[t + off]; __syncthreads(); }
  const float crv = red[0]; __syncthreads();
  const float mu = s / crv;
  if (FINAL) { mu_out[k * DIM + t] = mu; return; }
  red[t] = mu * mu; __syncthreads();
#pragma unroll
  for (int off = 128; off > 0; off >>= 1) { if (t < off) red[t] += red[t + off]; __syncthreads(); }
  const float inv = 1.0f / fmaxf(sqrtf(red[0]), EPSV);
  muT[t * KC + k] = mu * inv;
}

// ================= launch =================
extern "C" void kernel_launch(void* const* d_in, const int* in_sizes, int n_in,
                              void* d_out, int out_size, void* d_ws, size_t ws_size,
                              hipStream_t stream) {
  const float* embeds = (const float*)d_in[0];
  const float* init = (const float*)d_in[1];
  const float* beta = (const float*)d_in[2];
  float* out_mu = (float*)d_out;
  float* out_r = out_mu + KC * DIM;
  char* ws = (char*)d_ws;

  const size_t szX = (size_t)N_ROWS * DIM * 2;      // 102.4 MB
  const size_t szInv = (size_t)N_ROWS * 4;          // 800 KB
  const size_t szMuR = (size_t)KC * DIM * 4;        // 64 KB fp32 raw mu
  const size_t szSsq = (size_t)KC * 4 * 4;          // 1 KB quarter sumsq
  const size_t szPC = (size_t)NB * KC * DIM * 4;    // 16.8 MB
  const size_t szPR = (size_t)KC * NB * 4;          // 64 KB transposed cr
  const size_t need = szX + szInv + szMuR + szSsq + szPC + szPR;

  if (ws_size >= need) {
    char* pp = ws;
    _Float16* Xh = (_Float16*)pp; pp += szX;
    float* invn = (float*)pp; pp += szInv;
    float* mu_raw = (float*)pp; pp += szMuR;
    float* mu_ssq = (float*)pp; pp += szSsq;
    float* pcm = (float*)pp; pp += szPC;
    float* pcrt = (float*)pp;

    // iteration 0: prep fused (computes inv_norm, writes Xh, produces partials)
    cluster_first<<<NB, 512, 0, stream>>>(embeds, init, beta, Xh, invn, pcm, pcrt);
    for (int it = 1; it < NUM_ITER; ++it) {
      reduce_mu<0><<<dim3(KC, 4), 256, 0, stream>>>(pcm, pcrt, mu_raw, mu_ssq, nullptr);
      if (it == NUM_ITER - 1)
        cluster_main8<1><<<NB, 512, 0, stream>>>(Xh, invn, beta, mu_raw, mu_ssq,
                                                 pcm, pcrt, out_r);
      else
        cluster_main8<0><<<NB, 512, 0, stream>>>(Xh, invn, beta, mu_raw, mu_ssq,
                                                 pcm, pcrt, out_r);
    }
    reduce_mu<1><<<dim3(KC, 4), 256, 0, stream>>>(pcm, pcrt, nullptr, nullptr, out_mu);
  } else {
    // v1 fp32 fallback
    float* wsf = (float*)d_ws;
    float* muT = wsf;
    float* invn = muT + DIM * KC;
    size_t avail = ws_size / sizeof(float);
    size_t fixed = (size_t)DIM * KC + N_ROWS;
    size_t per_blk = (size_t)KC * DIM + KC;
    int nb = 256;
    if (avail > fixed) {
      size_t mx = (avail - fixed) / per_blk;
      if (mx < 256) nb = (int)mx;
    } else nb = 1;
    if (nb < 1) nb = 1;
    float* pcm = invn + N_ROWS;
    float* pcr = pcm + (size_t)nb * KC * DIM;

    rownorm_v1<<<2048, 256, 0, stream>>>(embeds, invn);
    prep0_v1<<<KC, 64, 0, stream>>>(init, muT);
    for (int it = 0; it < NUM_ITER; ++it) {
      if (it > 0) reduce_v1<0><<<KC, 256, 0, stream>>>(pcm, pcr, muT, nullptr, nb);
      if (it == NUM_ITER - 1)
        main_v1<1><<<nb, 256, 0, stream>>>(embeds, invn, muT, beta, pcm, pcr, out_r, nb);
      else
        main_v1<0><<<nb, 256, 0, stream>>>(embeds, invn, muT, beta, pcm, pcr, nullptr, nb);
    }
    reduce_v1<1><<<KC, 256, 0, stream>>>(pcm, pcr, muT, out_mu, nb);
  }
}

// Round 12
// 489.575 us; speedup vs baseline: 1.1466x; 1.1466x over previous
//
#include <hip/hip_runtime.h>
#include <math.h>

// Clusterator soft k-means: N=200000, D=256, K=64, 11 iterations.
// v14 = v11 RESTORED VERBATIM (491.9us session best).
//   v11: v9 structure (512-thr main, K-split GEMM1 + dist exchange,
//   softmax||transpose, N-split GEMM2, amreg mu hoist) + prep fused into
//   iteration 0 (cluster_first: stages fp32 embeds, computes inv_norm,
//   converts to f16, writes Xh, runs the identical tile body).
// Rounds 10-11 lesson: both perturbations of cluster_first's convert pass
//   (stage overlap, read/write visit-order changes) regressed via L2
//   partial-sector write amplification (WRITE_SIZE 118->195-200MB) -- the
//   sector-retirement timing is compiler-scheduling-sensitive; v11's exact
//   code retires cleanly. LDS b128 "conflicts" here are at the 8-cycle b128
//   floor regardless of order (counter does not correlate with time).
// Failed structural lessons: v4 persistent grid-barrier (-655), v6 full-K
//   wave-special (-64), v7 3-buf counted vmcnt (-39), v8/v10 2-blocks/CU
//   (-426/-540, VGPR spill; direction closed).
// v1 fallback (round-1 fp32 kernel) if ws_size too small.

#define N_ROWS 200000
#define DIM 256
#define KC 64
#define NUM_ITER 11
#define TR 64
#define NTILES (N_ROWS / TR)  // 3125
#define EPSV 1e-8f
#define NB 256

typedef _Float16 half8 __attribute__((ext_vector_type(8)));
typedef _Float16 half4 __attribute__((ext_vector_type(4)));
typedef float f32x4 __attribute__((ext_vector_type(4)));

typedef __attribute__((address_space(3))) void as3_void;
typedef __attribute__((address_space(1))) void as1_void;

__device__ __forceinline__ void glds16(const void* g, void* l) {
  __builtin_amdgcn_global_load_lds((const as1_void*)g, (as3_void*)l, 16, 0, 0);
}

__device__ __forceinline__ float wave_reduce_sum(float v) {
#pragma unroll
  for (int off = 32; off > 0; off >>= 1) v += __shfl_xor(v, off, 64);
  return v;
}

// LDS-only barrier: orders ds_write -> barrier -> ds_read across waves without
// draining vmcnt (global_load_lds prefetches stay in flight across it).
__device__ __forceinline__ void barrier_lgkm_only() {
  __builtin_amdgcn_sched_barrier(0);
  asm volatile("s_waitcnt lgkmcnt(0)" ::: "memory");
  __builtin_amdgcn_s_barrier();
  __builtin_amdgcn_sched_barrier(0);
}

// ---------------- staging helper (8-wave) ----------------
// 512B-row arrays (X tile rows): 32 x 1KB chunks, swizzled source, 4/wave.
// LDS layout: elem(row,dim) at [row*DIM + (dim ^ ((row&7)<<3))]
__device__ __forceinline__ void stage_row512_8(const _Float16* g, _Float16* l,
                                               int wid, int lane) {
#pragma unroll
  for (int ii = 0; ii < 4; ++ii) {
    int i = wid * 4 + ii;
    int row = i * 2 + (lane >> 5);
    int slot = (lane & 31) ^ (row & 7);
    glds16((const char*)g + row * 512 + slot * 16, (char*)l + i * 1024);
  }
}

// ---------------- iteration-0 kernel: fp32 in, prep fused ----------------
__global__ __launch_bounds__(512, 1) void cluster_first(
    const float* __restrict__ embeds, const float* __restrict__ init,
    const float* __restrict__ beta, _Float16* __restrict__ Xh,
    float* __restrict__ inv_norm, float* __restrict__ part_cm,
    float* __restrict__ part_crt) {
  __shared__ alignas(16) _Float16 x_lds[2][TR * DIM];    // 64KB: f32 stage, then XT target
  __shared__ alignas(16) _Float16 xt_lds[DIM * TR];      // 32KB: f16 X tile [row][dim] swz
  __shared__ alignas(16) _Float16 mu_lds[KC * DIM];      // 32KB [cl][dim] swz
  __shared__ alignas(16) _Float16 r_lds[KC * TR];        // 8KB  [cl][row] swz
  __shared__ alignas(16) f32x4 dist_lds[16 * 64];        // 16KB K-split partials
  __shared__ float cr_lds[4 * KC];                       // 1KB
  __shared__ float inv_lds[TR];                          // per-tile row inv

  float* x32 = (float*)&x_lds[0][0];        // 16384 f32 = 64 rows x 1KB
  _Float16* xtile = xt_lds;                 // f16 X tile (v9 x layout)
  _Float16* xtr = &x_lds[0][0];             // XT target (v9 xt layout)

  const int tid = threadIdx.x, wid = tid >> 6, lane = tid & 63;
  const int l15 = lane & 15, h = lane >> 4;
  const int kh = wid >> 2, rg = wid & 3;
  const float b = beta[0];
  const int myrow = 16 * rg + l15;
  const int rb0 = blockIdx.x;

  // ===== mu prologue from init (fp32): ssq -> rsqrt -> normalized f16 =====
  {
    const int cl = tid >> 3, sub = tid & 7;
    float ss = 0.f;
#pragma unroll
    for (int j = 0; j < 8; ++j) {
      float4 v = *(const float4*)(init + (size_t)cl * DIM + sub * 32 + 4 * j);
      ss = fmaf(v.x, v.x, ss); ss = fmaf(v.y, v.y, ss);
      ss = fmaf(v.z, v.z, ss); ss = fmaf(v.w, v.w, ss);
    }
    ss += __shfl_xor(ss, 1); ss += __shfl_xor(ss, 2); ss += __shfl_xor(ss, 4);
    if (sub == 0) cr_lds[cl] = ss;
  }
  __syncthreads();
  if (tid < KC) cr_lds[tid] = 1.0f / fmaxf(sqrtf(cr_lds[tid]), EPSV);
  __syncthreads();
  {
    const float4* init4 = (const float4*)init;
#pragma unroll
    for (int i = 0; i < 8; ++i) {
      const int idx = tid + 512 * i;
      const int cl = idx >> 6;
      const int dim0 = (idx & 63) * 4;
      float4 v = init4[idx];
      const float iv = cr_lds[cl];
      const int sw = dim0 ^ ((cl & 7) << 3);
      half4 hh;
      hh[0] = (_Float16)(v.x * iv); hh[1] = (_Float16)(v.y * iv);
      hh[2] = (_Float16)(v.z * iv); hh[3] = (_Float16)(v.w * iv);
      *(half4*)&mu_lds[cl * DIM + sw] = hh;
    }
  }
  __syncthreads();
  half8 amreg[4][4];  // K-split mu fragments (v9)
#pragma unroll
  for (int t = 0; t < 4; ++t) {
    const int kb = 128 * kh + 32 * t + 8 * h;
#pragma unroll
    for (int m = 0; m < 4; ++m) {
      const int cl = 16 * m + l15;
      amreg[t][m] = *(const half8*)&mu_lds[cl * DIM + (kb ^ ((cl & 7) << 3))];
    }
  }

  f32x4 acc2[4][2] = {};
  float cr_acc[16] = {};
  for (int rb = rb0; rb < NTILES; rb += NB) {
    // ---- stage fp32 tile: 64 rows x 1KB, one row per chunk, 8/wave ----
#pragma unroll
    for (int ii = 0; ii < 8; ++ii) {
      const int row = wid * 8 + ii;
      const int slot = lane ^ (row & 7);
      glds16((const char*)embeds + (size_t)(rb * TR + row) * 1024 + slot * 16,
             (char*)x32 + row * 1024);
    }
    __syncthreads();  // f32 staged (vmcnt drained by barrier semantics)

    // ---- fused pass: row ssq + f16 convert (LDS + global Xh) + inv ----
    {
      const int row = tid >> 3, sub = tid & 7;
      float ss = 0.f;
      half8 hh[4];
#pragma unroll
      for (int i2 = 0; i2 < 8; ++i2) {
        const int g = sub * 8 + i2;
        float4 v = *(const float4*)((const char*)x32 + row * 1024 +
                                    ((g ^ (row & 7)) * 16));
        ss = fmaf(v.x, v.x, ss); ss = fmaf(v.y, v.y, ss);
        ss = fmaf(v.z, v.z, ss); ss = fmaf(v.w, v.w, ss);
        _Float16* hp = (_Float16*)&hh[i2 >> 1] + (i2 & 1) * 4;
        hp[0] = (_Float16)v.x; hp[1] = (_Float16)v.y;
        hp[2] = (_Float16)v.z; hp[3] = (_Float16)v.w;
      }
#pragma unroll
      for (int j = 0; j < 4; ++j) {
        const int slot = (sub * 4 + j) ^ (row & 7);
        *(half8*)((char*)xtile + row * 512 + slot * 16) = hh[j];
        *(float4*)((char*)Xh + (size_t)(rb * TR + row) * 512 + sub * 64 + j * 16) =
            *(float4*)&hh[j];
      }
      ss += __shfl_xor(ss, 1); ss += __shfl_xor(ss, 2); ss += __shfl_xor(ss, 4);
      if (sub == 0) {
        const float iv = 1.0f / fmaxf(sqrtf(ss), EPSV);
        inv_lds[row] = iv;
        inv_norm[rb * TR + row] = iv;
      }
    }
    barrier_lgkm_only();  // xtile + inv_lds visible (Xh stores stay in flight)

    // ---- GEMM1 (K-split, v9 body; xb = xtile) ----
    f32x4 acc1[4] = {};
#pragma unroll
    for (int t = 0; t < 4; ++t) {
      const int kb = 128 * kh + 32 * t + 8 * h;
      half8 bx = *(const half8*)&xtile[myrow * DIM + (kb ^ ((myrow & 7) << 3))];
#pragma unroll
      for (int m = 0; m < 4; ++m)
        acc1[m] = __builtin_amdgcn_mfma_f32_16x16x32_f16(amreg[t][m], bx, acc1[m], 0, 0, 0);
    }
    if (kh) {
#pragma unroll
      for (int m = 0; m < 4; ++m) dist_lds[(rg * 4 + m) * 64 + lane] = acc1[m];
    }
    barrier_lgkm_only();  // bar1

    if (!kh) {
      // ---- combine + softmax (waves 0-3); inv from LDS ----
#pragma unroll
      for (int m = 0; m < 4; ++m) acc1[m] += dist_lds[(rg * 4 + m) * 64 + lane];
      const float sc = b * inv_lds[myrow];
#pragma unroll
      for (int m = 0; m < 4; ++m)
#pragma unroll
        for (int j = 0; j < 4; ++j) acc1[m][j] *= sc;
      float mx = -1e30f;
#pragma unroll
      for (int m = 0; m < 4; ++m)
#pragma unroll
        for (int j = 0; j < 4; ++j) mx = fmaxf(mx, acc1[m][j]);
      mx = fmaxf(mx, __shfl_xor(mx, 16));
      mx = fmaxf(mx, __shfl_xor(mx, 32));
      float esum = 0.f;
#pragma unroll
      for (int m = 0; m < 4; ++m)
#pragma unroll
        for (int j = 0; j < 4; ++j) {
          float e = __expf(acc1[m][j] - mx);
          acc1[m][j] = e;
          esum += e;
        }
      esum += __shfl_xor(esum, 16);
      esum += __shfl_xor(esum, 32);
      const float rcp = 1.0f / esum;
#pragma unroll
      for (int m = 0; m < 4; ++m)
#pragma unroll
        for (int j = 0; j < 4; ++j) {
          const float rv = acc1[m][j] * rcp;
          const int cl = 16 * m + 4 * h + j;
          cr_acc[m * 4 + j] += rv;
          r_lds[cl * TR + (myrow ^ ((cl & 7) << 3))] = (_Float16)rv;
        }
    } else {
      // ---- in-LDS transpose xtile -> xtr (waves 4-7, v9 body) ----
      const int t8 = tid & 255;
      const int db = t8 >> 3, rb8 = t8 & 7;
      union U { uint4 v; unsigned u[4]; };
      U tin[8];
#pragma unroll
      for (int k2 = 0; k2 < 8; ++k2)
        tin[k2].v = *(const uint4*)&xtile[(8 * rb8 + k2) * DIM + ((8 * db) ^ (k2 << 3))];
#pragma unroll
      for (int j = 0; j < 8; ++j) {
        const unsigned sel = (j & 1) ? 0x07060302u : 0x05040100u;
        U o;
#pragma unroll
        for (int m2 = 0; m2 < 4; ++m2)
          o.u[m2] = __builtin_amdgcn_perm(tin[2 * m2 + 1].u[j >> 1],
                                          tin[2 * m2].u[j >> 1], sel);
        *(uint4*)&xtr[(8 * db + j) * TR + 8 * (rb8 ^ j)] = o.v;
      }
    }
    barrier_lgkm_only();  // bar2: r_lds + xtr visible

    // ---- GEMM2 (N-split, v9 body; bx2 from xtr) ----
#pragma unroll
    for (int t = 0; t < 2; ++t) {
      const int kb = 32 * t + 8 * h;
      half8 ar[4], bx2[2];
#pragma unroll
      for (int m = 0; m < 4; ++m) {
        const int cl = 16 * m + l15;
        ar[m] = *(const half8*)&r_lds[cl * TR + (kb ^ ((cl & 7) << 3))];
      }
#pragma unroll
      for (int n = 0; n < 2; ++n) {
        const int dm = 32 * wid + 16 * n + l15;
        bx2[n] = *(const half8*)&xtr[dm * TR + (kb ^ ((dm & 7) << 3))];
      }
#pragma unroll
      for (int m = 0; m < 4; ++m)
#pragma unroll
        for (int n = 0; n < 2; ++n)
          acc2[m][n] = __builtin_amdgcn_mfma_f32_16x16x32_f16(ar[m], bx2[n], acc2[m][n], 0, 0, 0);
    }
    __syncthreads();  // tile end: xtr/x32 free; Xh stores drained
  }

  // ===== epilogue (v9) =====
  float* pc = part_cm + (size_t)blockIdx.x * (KC * DIM);
#pragma unroll
  for (int m = 0; m < 4; ++m)
#pragma unroll
    for (int n = 0; n < 2; ++n)
#pragma unroll
      for (int j = 0; j < 4; ++j)
        pc[(16 * m + 4 * h + j) * DIM + 32 * wid + 16 * n + l15] = acc2[m][n][j];
  if (wid < 4) {
#pragma unroll
    for (int m = 0; m < 4; ++m)
#pragma unroll
      for (int j = 0; j < 4; ++j) {
        float v = cr_acc[m * 4 + j];
        v += __shfl_xor(v, 1); v += __shfl_xor(v, 2);
        v += __shfl_xor(v, 4); v += __shfl_xor(v, 8);
        if (l15 == 0) cr_lds[wid * KC + 16 * m + 4 * h + j] = v;
      }
  }
  __syncthreads();
  if (wid == 0)
    part_crt[(size_t)lane * NB + blockIdx.x] =
        cr_lds[lane] + cr_lds[KC + lane] + cr_lds[2 * KC + lane] + cr_lds[3 * KC + lane];
}

// ---------------- main kernel (iterations 1..10): v9 VERBATIM ----------------
template <int LAST>
__global__ __launch_bounds__(512, 2) void cluster_main8(
    const _Float16* __restrict__ Xh, const float* __restrict__ inv_norm,
    const float* __restrict__ beta, const float* __restrict__ mu_raw,
    const float* __restrict__ mu_ssq, float* __restrict__ part_cm,
    float* __restrict__ part_crt, float* __restrict__ r_out) {
  __shared__ alignas(16) _Float16 mu_lds[KC * DIM];      // 32KB [cl][dim] swz
  __shared__ alignas(16) _Float16 x_lds[2][TR * DIM];    // 64KB [row][dim] swz
  __shared__ alignas(16) _Float16 xt_lds[DIM * TR];      // 32KB [dim][row] swz
  __shared__ alignas(16) _Float16 r_lds[KC * TR];        // 8KB  [cl][row] swz
  __shared__ alignas(16) f32x4 dist_lds[16 * 64];        // 16KB K-split partials
  __shared__ float cr_lds[4 * KC];                       // 1KB  mu inv / cr

  const int tid = threadIdx.x, wid = tid >> 6, lane = tid & 63;
  const int l15 = lane & 15, h = lane >> 4;
  const int kh = wid >> 2, rg = wid & 3;  // K-half, row-group
  const float b = beta[0];
  const int myrow = 16 * rg + l15;  // tile-local row this lane owns
  const int rb0 = blockIdx.x;

  // first X tile in flight
  stage_row512_8(Xh + (size_t)rb0 * TR * DIM, x_lds[0], wid, lane);

  // ===== mu prologue: normalize raw fp32 mu while staging into LDS =====
  if (tid < KC) {
    const float4 s4 = *(const float4*)&mu_ssq[4 * tid];
    cr_lds[tid] = 1.0f / fmaxf(sqrtf(s4.x + s4.y + s4.z + s4.w), EPSV);
  }
  __syncthreads();
  {
    const float4* mu_raw4 = (const float4*)mu_raw;
#pragma unroll
    for (int i = 0; i < 8; ++i) {
      const int idx = tid + 512 * i;          // 4096 float4 total
      const int cl = idx >> 6;                // 64 float4 per cluster row
      const int dim0 = (idx & 63) * 4;
      float4 v = mu_raw4[idx];
      const float iv = cr_lds[cl];
      const int sw = dim0 ^ ((cl & 7) << 3);
      half4 hh;
      hh[0] = (_Float16)(v.x * iv); hh[1] = (_Float16)(v.y * iv);
      hh[2] = (_Float16)(v.z * iv); hh[3] = (_Float16)(v.w * iv);
      *(half4*)&mu_lds[cl * DIM + sw] = hh;
    }
  }
  __syncthreads();  // mu_lds ready; x_lds[0] staging drained (vmcnt0)

  // hoist this wave's 16 loop-invariant mu fragments to registers.
  half8 amreg[4][4];
#pragma unroll
  for (int t = 0; t < 4; ++t) {
    const int kb = 128 * kh + 32 * t + 8 * h;
#pragma unroll
    for (int m = 0; m < 4; ++m) {
      const int cl = 16 * m + l15;
      amreg[t][m] = *(const half8*)&mu_lds[cl * DIM + (kb ^ ((cl & 7) << 3))];
    }
  }

  f32x4 acc2[4][2] = {};
  float cr_acc[16] = {};
  int p = 0;
  for (int rb = rb0; rb < NTILES; rb += NB, p ^= 1) {
    const int row0 = rb * TR;
    const int rbn = rb + NB;
    if (rbn < NTILES)  // prefetch next X tile into other buffer
      stage_row512_8(Xh + (size_t)rbn * TR * DIM, x_lds[p ^ 1], wid, lane);

    // ---- GEMM1 (K-split): mu from regs -> 4 LDS reads per wave ----
    f32x4 acc1[4] = {};
    const _Float16* xb = x_lds[p];
#pragma unroll
    for (int t = 0; t < 4; ++t) {
      const int kb = 128 * kh + 32 * t + 8 * h;
      half8 bx = *(const half8*)&xb[myrow * DIM + (kb ^ ((myrow & 7) << 3))];
#pragma unroll
      for (int m = 0; m < 4; ++m)
        acc1[m] = __builtin_amdgcn_mfma_f32_16x16x32_f16(amreg[t][m], bx, acc1[m], 0, 0, 0);
    }
    if (kh) {  // publish K-half partials
#pragma unroll
      for (int m = 0; m < 4; ++m) dist_lds[(rg * 4 + m) * 64 + lane] = acc1[m];
    }
    barrier_lgkm_only();  // bar1: dist partials visible; X prefetch in flight

    if (!kh) {
      // ---- combine + softmax over 64 clusters (waves 0-3) ----
#pragma unroll
      for (int m = 0; m < 4; ++m) acc1[m] += dist_lds[(rg * 4 + m) * 64 + lane];
      const int xr = row0 + myrow;
      const float sc = b * inv_norm[xr];
#pragma unroll
      for (int m = 0; m < 4; ++m)
#pragma unroll
        for (int j = 0; j < 4; ++j) acc1[m][j] *= sc;
      float mx = -1e30f;
#pragma unroll
      for (int m = 0; m < 4; ++m)
#pragma unroll
        for (int j = 0; j < 4; ++j) mx = fmaxf(mx, acc1[m][j]);
      mx = fmaxf(mx, __shfl_xor(mx, 16));
      mx = fmaxf(mx, __shfl_xor(mx, 32));
      float esum = 0.f;
#pragma unroll
      for (int m = 0; m < 4; ++m)
#pragma unroll
        for (int j = 0; j < 4; ++j) {
          float e = __expf(acc1[m][j] - mx);
          acc1[m][j] = e;
          esum += e;
        }
      esum += __shfl_xor(esum, 16);
      esum += __shfl_xor(esum, 32);
      const float rcp = 1.0f / esum;
#pragma unroll
      for (int m = 0; m < 4; ++m) {
#pragma unroll
        for (int j = 0; j < 4; ++j) {
          const float rv = acc1[m][j] * rcp;
          acc1[m][j] = rv;
          const int cl = 16 * m + 4 * h + j;
          cr_acc[m * 4 + j] += rv;
          r_lds[cl * TR + (myrow ^ ((cl & 7) << 3))] = (_Float16)rv;
        }
        if (LAST)  // coalesced 16B store
          *(float4*)&r_out[(size_t)xr * KC + 16 * m + 4 * h] = *(float4*)&acc1[m];
      }
    } else {
      // ---- in-LDS transpose x[p] -> xt_lds (waves 4-7, 8x8 via v_perm) ----
      const int t8 = tid & 255;
      const int db = t8 >> 3, rb8 = t8 & 7;
      union U { uint4 v; unsigned u[4]; };
      U tin[8];
#pragma unroll
      for (int k2 = 0; k2 < 8; ++k2)  // row = 8*rb8+k2 -> row&7 == k2
        tin[k2].v = *(const uint4*)&xb[(8 * rb8 + k2) * DIM + ((8 * db) ^ (k2 << 3))];
#pragma unroll
      for (int j = 0; j < 8; ++j) {
        const unsigned sel = (j & 1) ? 0x07060302u : 0x05040100u;
        U o;
#pragma unroll
        for (int m2 = 0; m2 < 4; ++m2)
          o.u[m2] = __builtin_amdgcn_perm(tin[2 * m2 + 1].u[j >> 1],
                                          tin[2 * m2].u[j >> 1], sel);
        *(uint4*)&xt_lds[(8 * db + j) * TR + 8 * (rb8 ^ j)] = o.v;
      }
    }

    barrier_lgkm_only();  // bar2: r_lds + xt_lds visible

    // ---- GEMM2 (N-split): wave wid owns dims 32*wid..+31 ----
#pragma unroll
    for (int t = 0; t < 2; ++t) {
      const int kb = 32 * t + 8 * h;
      half8 ar[4], bx2[2];
#pragma unroll
      for (int m = 0; m < 4; ++m) {
        const int cl = 16 * m + l15;
        ar[m] = *(const half8*)&r_lds[cl * TR + (kb ^ ((cl & 7) << 3))];
      }
#pragma unroll
      for (int n = 0; n < 2; ++n) {
        const int dm = 32 * wid + 16 * n + l15;
        bx2[n] = *(const half8*)&xt_lds[dm * TR + (kb ^ ((dm & 7) << 3))];
      }
#pragma unroll
      for (int m = 0; m < 4; ++m)
#pragma unroll
        for (int n = 0; n < 2; ++n)
          acc2[m][n] = __builtin_amdgcn_mfma_f32_16x16x32_f16(ar[m], bx2[n], acc2[m][n], 0, 0, 0);
    }
    // sync2: full drain -- next tile needs x[p^1] staged for all waves.
    __syncthreads();
  }

  // ===== epilogue: per-block partials =====
  float* pc = part_cm + (size_t)blockIdx.x * (KC * DIM);
#pragma unroll
  for (int m = 0; m < 4; ++m)
#pragma unroll
    for (int n = 0; n < 2; ++n)
#pragma unroll
      for (int j = 0; j < 4; ++j)
        pc[(16 * m + 4 * h + j) * DIM + 32 * wid + 16 * n + l15] = acc2[m][n][j];
  if (wid < 4) {
#pragma unroll
    for (int m = 0; m < 4; ++m)
#pragma unroll
      for (int j = 0; j < 4; ++j) {
        float v = cr_acc[m * 4 + j];
        v += __shfl_xor(v, 1); v += __shfl_xor(v, 2);
        v += __shfl_xor(v, 4); v += __shfl_xor(v, 8);
        if (l15 == 0) cr_lds[wid * KC + 16 * m + 4 * h + j] = v;
      }
  }
  __syncthreads();
  if (wid == 0)
    part_crt[(size_t)lane * NB + blockIdx.x] =  // transposed: [cl][block]
        cr_lds[lane] + cr_lds[KC + lane] + cr_lds[2 * KC + lane] + cr_lds[3 * KC + lane];
}

// ---------------- reduce: grid (KC,4), one (cluster, dim-quarter)/block ----
template <int FINAL>
__global__ void reduce_mu(const float* __restrict__ part_cm,
                          const float* __restrict__ part_crt,
                          float* __restrict__ mu_raw, float* __restrict__ mu_ssq,
                          float* __restrict__ mu_out) {
  const int cl = blockIdx.x, q = blockIdx.y;
  const int tid = threadIdx.x, wid = tid >> 6, lane = tid & 63;
  __shared__ float red2[4 * 64];
  __shared__ float cr4[4];
  float c = part_crt[(size_t)cl * NB + tid];  // coalesced 1KB
  c = wave_reduce_sum(c);
  if (lane == 0) cr4[wid] = c;
  float s = 0.f;
  const float* basep =
      part_cm + (size_t)(64 * wid) * (KC * DIM) + cl * DIM + 64 * q + lane;
#pragma unroll 8
  for (int i = 0; i < 64; ++i) s += basep[(size_t)i * (KC * DIM)];
  red2[wid * 64 + lane] = s;
  __syncthreads();
  if (wid == 0) {
    const float crv = cr4[0] + cr4[1] + cr4[2] + cr4[3];
    const float st = red2[lane] + red2[64 + lane] + red2[128 + lane] + red2[192 + lane];
    const float mu = st / crv;
    const int dim = 64 * q + lane;
    if (FINAL) {
      mu_out[cl * DIM + dim] = mu;
    } else {
      mu_raw[cl * DIM + dim] = mu;
      float ss = wave_reduce_sum(mu * mu);
      if (lane == 0) mu_ssq[cl * 4 + q] = ss;
    }
  }
}

// ================= v1 fallback (round-1 fp32 path) =================
__global__ void rownorm_v1(const float* __restrict__ embeds, float* __restrict__ inv_norm) {
  int gw = (blockIdx.x * blockDim.x + threadIdx.x) >> 6;
  int lane = threadIdx.x & 63;
  int nw = (gridDim.x * blockDim.x) >> 6;
  for (int row = gw; row < N_ROWS; row += nw) {
    const float* rp = embeds + (size_t)row * DIM;
    float s = 0.f;
#pragma unroll
    for (int j = 0; j < 4; ++j) { float v = rp[lane + 64 * j]; s = fmaf(v, v, s); }
    s = wave_reduce_sum(s);
    if (lane == 0) inv_norm[row] = 1.0f / fmaxf(sqrtf(s), EPSV);
  }
}
__global__ void prep0_v1(const float* __restrict__ init, float* __restrict__ muT) {
  int k = blockIdx.x, lane = threadIdx.x;
  const float* rp = init + k * DIM;
  float v[4]; float s = 0.f;
#pragma unroll
  for (int j = 0; j < 4; ++j) { v[j] = rp[lane + 64 * j]; s = fmaf(v[j], v[j], s); }
  s = wave_reduce_sum(s);
  float inv = 1.0f / fmaxf(sqrtf(s), EPSV);
#pragma unroll
  for (int j = 0; j < 4; ++j) muT[(lane + 64 * j) * KC + k] = v[j] * inv;
}
__device__ __forceinline__ float wave_reduce_max_v1(float v) {
#pragma unroll
  for (int off = 32; off > 0; off >>= 1) v = fmaxf(v, __shfl_xor(v, off, 64));
  return v;
}
template <int LAST>
__global__ __launch_bounds__(256, 1) void main_v1(
    const float* __restrict__ embeds, const float* __restrict__ inv_norm,
    const float* __restrict__ muT, const float* __restrict__ beta,
    float* __restrict__ part_cm, float* __restrict__ part_cr,
    float* __restrict__ r_out, int nb) {
  __shared__ float mu_l[DIM * KC];
  __shared__ float x_l[TR * DIM];
  __shared__ float r_l[TR * KC];
  __shared__ float cr_l[4 * KC];
  const int tid = threadIdx.x, wid = tid >> 6, lane = tid & 63;
  const float b = beta[0];
  {
    const float4* m4 = (const float4*)muT; float4* ml4 = (float4*)mu_l;
#pragma unroll
    for (int i = 0; i < 16; ++i) ml4[tid + i * 256] = m4[tid + i * 256];
  }
  float acc[64];
#pragma unroll
  for (int i = 0; i < 64; ++i) acc[i] = 0.f;
  float cr = 0.f;
  for (int rb = blockIdx.x; rb < NTILES; rb += nb) {
    const int row0 = rb * TR;
    __syncthreads();
    {
      const float4* x4 = (const float4*)(embeds + (size_t)row0 * DIM);
      float4* xl4 = (float4*)x_l;
#pragma unroll
      for (int i = 0; i < 16; ++i) xl4[tid + i * 256] = x4[tid + i * 256];
    }
    __syncthreads();
    float dist[16];
#pragma unroll
    for (int r = 0; r < 16; ++r) dist[r] = 0.f;
    const int rbase = wid * 16;
    for (int d = 0; d < DIM; d += 4) {
      float mv0 = mu_l[(d + 0) * KC + lane], mv1 = mu_l[(d + 1) * KC + lane];
      float mv2 = mu_l[(d + 2) * KC + lane], mv3 = mu_l[(d + 3) * KC + lane];
#pragma unroll
      for (int r = 0; r < 16; ++r) {
        float4 xv = *(const float4*)&x_l[(rbase + r) * DIM + d];
        dist[r] = fmaf(xv.x, mv0, dist[r]); dist[r] = fmaf(xv.y, mv1, dist[r]);
        dist[r] = fmaf(xv.z, mv2, dist[r]); dist[r] = fmaf(xv.w, mv3, dist[r]);
      }
    }
#pragma unroll
    for (int r = 0; r < 16; ++r) {
      const int row = rbase + r;
      float s = b * (dist[r] * inv_norm[row0 + row]);
      float m = wave_reduce_max_v1(s);
      float e = __expf(s - m);
      float sum = wave_reduce_sum(e);
      float rv = e * (1.0f / sum);
      cr += rv;
      r_l[row * KC + lane] = rv;
      if (LAST) r_out[(size_t)(row0 + row) * KC + lane] = rv;
    }
    __syncthreads();
    const int dbase = wid * 64;
    for (int row = 0; row < TR; ++row) {
      float rv = r_l[row * KC + lane];
#pragma unroll
      for (int dd = 0; dd < 64; dd += 4) {
        float4 xv = *(const float4*)&x_l[row * DIM + dbase + dd];
        acc[dd + 0] = fmaf(rv, xv.x, acc[dd + 0]); acc[dd + 1] = fmaf(rv, xv.y, acc[dd + 1]);
        acc[dd + 2] = fmaf(rv, xv.z, acc[dd + 2]); acc[dd + 3] = fmaf(rv, xv.w, acc[dd + 3]);
      }
    }
  }
  {
    float* pp = part_cm + ((size_t)blockIdx.x * KC + lane) * DIM + wid * 64;
#pragma unroll
    for (int dd = 0; dd < 64; dd += 4)
      *(float4*)&pp[dd] = make_float4(acc[dd], acc[dd + 1], acc[dd + 2], acc[dd + 3]);
    cr_l[wid * KC + lane] = cr;
  }
  __syncthreads();
  if (wid == 0) {
    float c = cr_l[lane] + cr_l[64 + lane] + cr_l[128 + lane] + cr_l[192 + lane];
    part_cr[(size_t)blockIdx.x * KC + lane] = c;
  }
}
template <int FINAL>
__global__ void reduce_v1(const float* __restrict__ part_cm, const float* __restrict__ part_cr,
                          float* __restrict__ muT, float* __restrict__ mu_out, int nb) {
  const int k = blockIdx.x, t = threadIdx.x;
  __shared__ float red[256];
  float s = 0.f;
  for (int bl = 0; bl < nb; ++bl) s += part_cm[((size_t)bl * KC + k) * DIM + t];
  float c = 0.f;
  for (int bl = t; bl < nb; bl += 256) c += part_cr[(size_t)bl * KC + k];
  red[t] = c; __syncthreads();
#pragma unroll
  for (int off = 128; off > 0; off >>= 1) { if (t < off) red[t] += red[t + off]; __syncthreads(); }
  const float crv = red[0]; __syncthreads();
  const float mu = s / crv;
  if (FINAL) { mu_out[k * DIM + t] = mu; return; }
  red[t] = mu * mu; __syncthreads();
#pragma unroll
  for (int off = 128; off > 0; off >>= 1) { if (t < off) red[t] += red[t + off]; __syncthreads(); }
  const float inv = 1.0f / fmaxf(sqrtf(red[0]), EPSV);
  muT[t * KC + k] = mu * inv;
}

// ================= launch =================
extern "C" void kernel_launch(void* const* d_in, const int* in_sizes, int n_in,
                              void* d_out, int out_size, void* d_ws, size_t ws_size,
                              hipStream_t stream) {
  const float* embeds = (const float*)d_in[0];
  const float* init = (const float*)d_in[1];
  const float* beta = (const float*)d_in[2];
  float* out_mu = (float*)d_out;
  float* out_r = out_mu + KC * DIM;
  char* ws = (char*)d_ws;

  const size_t szX = (size_t)N_ROWS * DIM * 2;      // 102.4 MB
  const size_t szInv = (size_t)N_ROWS * 4;          // 800 KB
  const size_t szMuR = (size_t)KC * DIM * 4;        // 64 KB fp32 raw mu
  const size_t szSsq = (size_t)KC * 4 * 4;          // 1 KB quarter sumsq
  const size_t szPC = (size_t)NB * KC * DIM * 4;    // 16.8 MB
  const size_t szPR = (size_t)KC * NB * 4;          // 64 KB transposed cr
  const size_t need = szX + szInv + szMuR + szSsq + szPC + szPR;

  if (ws_size >= need) {
    char* pp = ws;
    _Float16* Xh = (_Float16*)pp; pp += szX;
    float* invn = (float*)pp; pp += szInv;
    float* mu_raw = (float*)pp; pp += szMuR;
    float* mu_ssq = (float*)pp; pp += szSsq;
    float* pcm = (float*)pp; pp += szPC;
    float* pcrt = (float*)pp;

    // iteration 0: prep fused (computes inv_norm, writes Xh, produces partials)
    cluster_first<<<NB, 512, 0, stream>>>(embeds, init, beta, Xh, invn, pcm, pcrt);
    for (int it = 1; it < NUM_ITER; ++it) {
      reduce_mu<0><<<dim3(KC, 4), 256, 0, stream>>>(pcm, pcrt, mu_raw, mu_ssq, nullptr);
      if (it == NUM_ITER - 1)
        cluster_main8<1><<<NB, 512, 0, stream>>>(Xh, invn, beta, mu_raw, mu_ssq,
                                                 pcm, pcrt, out_r);
      else
        cluster_main8<0><<<NB, 512, 0, stream>>>(Xh, invn, beta, mu_raw, mu_ssq,
                                                 pcm, pcrt, out_r);
    }
    reduce_mu<1><<<dim3(KC, 4), 256, 0, stream>>>(pcm, pcrt, nullptr, nullptr, out_mu);
  } else {
    // v1 fp32 fallback
    float* wsf = (float*)d_ws;
    float* muT = wsf;
    float* invn = muT + DIM * KC;
    size_t avail = ws_size / sizeof(float);
    size_t fixed = (size_t)DIM * KC + N_ROWS;
    size_t per_blk = (size_t)KC * DIM + KC;
    int nb = 256;
    if (avail > fixed) {
      size_t mx = (avail - fixed) / per_blk;
      if (mx < 256) nb = (int)mx;
    } else nb = 1;
    if (nb < 1) nb = 1;
    float* pcm = invn + N_ROWS;
    float* pcr = pcm + (size_t)nb * KC * DIM;

    rownorm_v1<<<2048, 256, 0, stream>>>(embeds, invn);
    prep0_v1<<<KC, 64, 0, stream>>>(init, muT);
    for (int it = 0; it < NUM_ITER; ++it) {
      if (it > 0) reduce_v1<0><<<KC, 256, 0, stream>>>(pcm, pcr, muT, nullptr, nb);
      if (it == NUM_ITER - 1)
        main_v1<1><<<nb, 256, 0, stream>>>(embeds, invn, muT, beta, pcm, pcr, out_r, nb);
      else
        main_v1<0><<<nb, 256, 0, stream>>>(embeds, invn, muT, beta, pcm, pcr, nullptr, nb);
    }
    reduce_v1<1><<<KC, 256, 0, stream>>>(pcm, pcr, muT, out_mu, nb);
  }
}